// Round 1
// baseline (1375.387 us; speedup 1.0000x reference)
//
#include <hip/hip_runtime.h>

#define N_NODES  100000
#define N_EDGES  1600000
#define DIM      128
#define N_GRAPHS 512

// ---------------- CSR build ----------------

__global__ __launch_bounds__(256) void count_kernel(const int* __restrict__ col,
                                                    int* __restrict__ cnt) {
    int e = blockIdx.x * 256 + threadIdx.x;
    if (e < N_EDGES) atomicAdd(&cnt[col[e]], 1);
}

__global__ __launch_bounds__(256) void dinv_kernel(const int* __restrict__ cnt,
                                                   float* __restrict__ dinv) {
    int i = blockIdx.x * 256 + threadIdx.x;
    if (i < N_NODES) dinv[i] = rsqrtf((float)(cnt[i] + 1));  // +1 = self loop
}

// single-block exclusive scan of cnt[0..N) -> off[0..N]
__global__ __launch_bounds__(1024) void scan_kernel(const int* __restrict__ cnt,
                                                    int* __restrict__ off) {
    __shared__ int sdata[1024];
    const int CH = 98;  // 1024*98 = 100352 >= 100000
    int t = threadIdx.x;
    int base = t * CH;
    int lsum = 0;
    for (int i = 0; i < CH; ++i) {
        int idx = base + i;
        if (idx < N_NODES) lsum += cnt[idx];
    }
    sdata[t] = lsum;
    __syncthreads();
    for (int o = 1; o < 1024; o <<= 1) {
        int v = (t >= o) ? sdata[t - o] : 0;
        __syncthreads();
        sdata[t] += v;
        __syncthreads();
    }
    int run = sdata[t] - lsum;  // exclusive prefix for this chunk
    for (int i = 0; i < CH; ++i) {
        int idx = base + i;
        if (idx < N_NODES) {
            off[idx] = run;
            run += cnt[idx];
        } else if (idx == N_NODES) {
            off[idx] = run;  // == total edges
        }
    }
}

__global__ __launch_bounds__(256) void fill_kernel(const int* __restrict__ row,
                                                   const int* __restrict__ col,
                                                   const int* __restrict__ off,
                                                   int* __restrict__ fill,
                                                   const float* __restrict__ dinv,
                                                   int* __restrict__ ssrc,
                                                   float* __restrict__ snorm) {
    int e = blockIdx.x * 256 + threadIdx.x;
    if (e < N_EDGES) {
        int r = row[e], c = col[e];
        int p = off[c] + atomicAdd(&fill[c], 1);
        ssrc[p]  = r;
        snorm[p] = dinv[r] * dinv[c];
    }
}

// ---------------- per-layer: aggregate then GEMM ----------------

// one wave per node; lane holds dims [2*lane, 2*lane+1]
__global__ __launch_bounds__(256) void agg_kernel(const float* __restrict__ h,
                                                  float* __restrict__ out,
                                                  const int* __restrict__ off,
                                                  const int* __restrict__ ssrc,
                                                  const float* __restrict__ snorm,
                                                  const float* __restrict__ dinv) {
    int node = blockIdx.x * 4 + (threadIdx.x >> 6);
    int lane = threadIdx.x & 63;
    const float2* hp = (const float2*)h;

    float di = dinv[node];
    float2 self = hp[(size_t)node * 64 + lane];
    float2 acc0, acc1;
    acc0.x = di * di * self.x;
    acc0.y = di * di * self.y;
    acc1.x = 0.f; acc1.y = 0.f;

    int beg = off[node], end = off[node + 1];
    int e = beg;
    for (; e + 3 < end; e += 4) {
        int   s0 = ssrc[e],     s1 = ssrc[e + 1], s2 = ssrc[e + 2], s3 = ssrc[e + 3];
        float w0 = snorm[e],    w1 = snorm[e + 1], w2 = snorm[e + 2], w3 = snorm[e + 3];
        float2 v0 = hp[(size_t)s0 * 64 + lane];
        float2 v1 = hp[(size_t)s1 * 64 + lane];
        float2 v2 = hp[(size_t)s2 * 64 + lane];
        float2 v3 = hp[(size_t)s3 * 64 + lane];
        acc0.x = fmaf(w0, v0.x, acc0.x); acc0.y = fmaf(w0, v0.y, acc0.y);
        acc1.x = fmaf(w1, v1.x, acc1.x); acc1.y = fmaf(w1, v1.y, acc1.y);
        acc0.x = fmaf(w2, v2.x, acc0.x); acc0.y = fmaf(w2, v2.y, acc0.y);
        acc1.x = fmaf(w3, v3.x, acc1.x); acc1.y = fmaf(w3, v3.y, acc1.y);
    }
    for (; e < end; ++e) {
        int s = ssrc[e];
        float w = snorm[e];
        float2 v = hp[(size_t)s * 64 + lane];
        acc0.x = fmaf(w, v.x, acc0.x); acc0.y = fmaf(w, v.y, acc0.y);
    }
    float2 o;
    o.x = acc0.x + acc1.x;
    o.y = acc0.y + acc1.y;
    ((float2*)out)[(size_t)node * 64 + lane] = o;
}

// C[m, j] = relu_opt( sum_k A[m,k] * W[k,j] + bias[j] ), tile 64 nodes x 128 outs
__global__ __launch_bounds__(256) void gemm_kernel(const float* __restrict__ A,
                                                   const float* __restrict__ W,
                                                   const float* __restrict__ bias,
                                                   float* __restrict__ out,
                                                   int do_relu) {
    __shared__ float sW[32][132];  // k-chunk x 128 outputs (+4 pad)
    __shared__ float sA[32][68];   // k-chunk x 64 nodes (+4 pad)
    int t  = threadIdx.x;
    int m0 = blockIdx.x * 64;
    int jt = (t & 15) * 8;   // output base for this thread
    int mt = (t >> 4) * 4;   // node base for this thread

    float acc[4][8];
#pragma unroll
    for (int i = 0; i < 4; ++i)
#pragma unroll
        for (int j = 0; j < 8; ++j) acc[i][j] = 0.f;

    for (int k0 = 0; k0 < 128; k0 += 32) {
        __syncthreads();
        {   // stage A chunk (transposed): 64 m x 32 k
            int ml = t >> 2, kl = (t & 3) * 8;
            int m = m0 + ml;
            float4 v0 = {0, 0, 0, 0}, v1 = {0, 0, 0, 0};
            if (m < N_NODES) {
                const float4* ap = (const float4*)(A + (size_t)m * 128 + k0 + kl);
                v0 = ap[0];
                v1 = ap[1];
            }
            sA[kl + 0][ml] = v0.x; sA[kl + 1][ml] = v0.y;
            sA[kl + 2][ml] = v0.z; sA[kl + 3][ml] = v0.w;
            sA[kl + 4][ml] = v1.x; sA[kl + 5][ml] = v1.y;
            sA[kl + 6][ml] = v1.z; sA[kl + 7][ml] = v1.w;
        }
        {   // stage W chunk: 32 k x 128 j
            int kw = t >> 3, jw = (t & 7) * 16;
            const float* wp = W + (size_t)(k0 + kw) * 128 + jw;
            float4 w0 = ((const float4*)wp)[0];
            float4 w1 = ((const float4*)wp)[1];
            float4 w2 = ((const float4*)wp)[2];
            float4 w3 = ((const float4*)wp)[3];
            *(float4*)&sW[kw][jw + 0]  = w0;
            *(float4*)&sW[kw][jw + 4]  = w1;
            *(float4*)&sW[kw][jw + 8]  = w2;
            *(float4*)&sW[kw][jw + 12] = w3;
        }
        __syncthreads();
#pragma unroll
        for (int kk = 0; kk < 32; ++kk) {
            float4 a  = *(const float4*)&sA[kk][mt];
            float4 w0 = *(const float4*)&sW[kk][jt];
            float4 w1 = *(const float4*)&sW[kk][jt + 4];
            float av[4] = {a.x, a.y, a.z, a.w};
            float wv[8] = {w0.x, w0.y, w0.z, w0.w, w1.x, w1.y, w1.z, w1.w};
#pragma unroll
            for (int i = 0; i < 4; ++i)
#pragma unroll
                for (int j = 0; j < 8; ++j)
                    acc[i][j] = fmaf(av[i], wv[j], acc[i][j]);
        }
    }

#pragma unroll
    for (int i = 0; i < 4; ++i) {
        int m = m0 + mt + i;
        if (m < N_NODES) {
            float4 o0, o1;
            o0.x = acc[i][0] + bias[jt + 0];
            o0.y = acc[i][1] + bias[jt + 1];
            o0.z = acc[i][2] + bias[jt + 2];
            o0.w = acc[i][3] + bias[jt + 3];
            o1.x = acc[i][4] + bias[jt + 4];
            o1.y = acc[i][5] + bias[jt + 5];
            o1.z = acc[i][6] + bias[jt + 6];
            o1.w = acc[i][7] + bias[jt + 7];
            if (do_relu) {
                o0.x = fmaxf(o0.x, 0.f); o0.y = fmaxf(o0.y, 0.f);
                o0.z = fmaxf(o0.z, 0.f); o0.w = fmaxf(o0.w, 0.f);
                o1.x = fmaxf(o1.x, 0.f); o1.y = fmaxf(o1.y, 0.f);
                o1.z = fmaxf(o1.z, 0.f); o1.w = fmaxf(o1.w, 0.f);
            }
            *(float4*)(out + (size_t)m * 128 + jt)     = o0;
            *(float4*)(out + (size_t)m * 128 + jt + 4) = o1;
        }
    }
}

// ---------------- pooling + MLP head ----------------

__global__ __launch_bounds__(256) void pool_kernel(const float* __restrict__ h,
                                                   const int* __restrict__ batch,
                                                   float* __restrict__ psum,
                                                   int* __restrict__ pcnt) {
    int node = blockIdx.x * 4 + (threadIdx.x >> 6);
    int lane = threadIdx.x & 63;
    int g = batch[node];
    const float2* hp = (const float2*)h;
    float2 v = hp[(size_t)node * 64 + lane];
    atomicAdd(&psum[(size_t)g * 128 + 2 * lane + 0], v.x);
    atomicAdd(&psum[(size_t)g * 128 + 2 * lane + 1], v.y);
    if (lane == 0) atomicAdd(&pcnt[g], 1);
}

__global__ __launch_bounds__(128) void mlp_kernel(const float* __restrict__ psum,
                                                  const int* __restrict__ pcnt,
                                                  const float* __restrict__ w1,
                                                  const float* __restrict__ b1,
                                                  const float* __restrict__ w2,
                                                  const float* __restrict__ b2,
                                                  float* __restrict__ out) {
    __shared__ float mean[128];
    __shared__ float hid[100];
    int g = blockIdx.x;
    int t = threadIdx.x;
    float c = fmaxf((float)pcnt[g], 1.0f);
    mean[t] = psum[(size_t)g * 128 + t] / c;
    __syncthreads();
    if (t < 100) {
        float s = b1[t];
        for (int k = 0; k < 128; ++k) s = fmaf(mean[k], w1[k * 100 + t], s);
        hid[t] = fmaxf(s, 0.f);
    }
    __syncthreads();
    if (t < 4) {
        float s = b2[t];
        for (int j = 0; j < 100; ++j) s = fmaf(hid[j], w2[j * 4 + t], s);
        out[(size_t)g * 4 + t] = s;
    }
}

// ---------------- launch ----------------

extern "C" void kernel_launch(void* const* d_in, const int* in_sizes, int n_in,
                              void* d_out, int out_size, void* d_ws, size_t ws_size,
                              hipStream_t stream) {
    const float* x   = (const float*)d_in[0];
    const float* Ws  = (const float*)d_in[1];
    const float* bs  = (const float*)d_in[2];
    const float* w1  = (const float*)d_in[3];
    const float* b1  = (const float*)d_in[4];
    const float* w2  = (const float*)d_in[5];
    const float* b2  = (const float*)d_in[6];
    const int*   ei  = (const int*)d_in[7];
    const int*   bat = (const int*)d_in[8];
    float* outp = (float*)d_out;

    char* p = (char*)d_ws;
    auto take = [&](size_t bytes) -> void* {
        void* r = (void*)p;
        p += (bytes + 255) & ~(size_t)255;
        return r;
    };
    int*   cnt   = (int*)take((size_t)N_NODES * 4);
    int*   fillc = (int*)take((size_t)N_NODES * 4);
    int*   csr   = (int*)take((size_t)(N_NODES + 1) * 4);
    float* dinv  = (float*)take((size_t)N_NODES * 4);
    int*   ssrc  = (int*)take((size_t)N_EDGES * 4);
    float* snorm = (float*)take((size_t)N_EDGES * 4);
    float* psum  = (float*)take((size_t)N_GRAPHS * 128 * 4);
    int*   pcnt  = (int*)take((size_t)N_GRAPHS * 4);
    float* bufA  = (float*)take((size_t)N_NODES * 128 * 4);
    float* bufB  = (float*)take((size_t)N_NODES * 128 * 4);

    const int* row = ei;
    const int* col = ei + N_EDGES;

    hipMemsetAsync(cnt,   0, (size_t)N_NODES * 4, stream);
    hipMemsetAsync(fillc, 0, (size_t)N_NODES * 4, stream);
    hipMemsetAsync(psum,  0, (size_t)N_GRAPHS * 128 * 4, stream);
    hipMemsetAsync(pcnt,  0, (size_t)N_GRAPHS * 4, stream);

    count_kernel<<<N_EDGES / 256, 256, 0, stream>>>(col, cnt);
    dinv_kernel<<<(N_NODES + 255) / 256, 256, 0, stream>>>(cnt, dinv);
    scan_kernel<<<1, 1024, 0, stream>>>(cnt, csr);
    fill_kernel<<<N_EDGES / 256, 256, 0, stream>>>(row, col, csr, fillc, dinv, ssrc, snorm);

    const float* hin = x;
    for (int L = 0; L < 4; ++L) {
        agg_kernel<<<N_NODES / 4, 256, 0, stream>>>(hin, bufB, csr, ssrc, snorm, dinv);
        gemm_kernel<<<(N_NODES + 63) / 64, 256, 0, stream>>>(
            bufB, Ws + (size_t)L * 128 * 128, bs + (size_t)L * 128, bufA, (L < 3) ? 1 : 0);
        hin = bufA;
    }
    pool_kernel<<<N_NODES / 4, 256, 0, stream>>>(bufA, bat, psum, pcnt);
    mlp_kernel<<<N_GRAPHS, 128, 0, stream>>>(psum, pcnt, w1, b1, w2, b2, outp);
}

// Round 2
// 1131.462 us; speedup vs baseline: 1.2156x; 1.2156x over previous
//
#include <hip/hip_runtime.h>

#define N_NODES  100000
#define N_EDGES  1600000
#define DIM      128
#define N_GRAPHS 512

// ---------------- CSR build ----------------

__global__ __launch_bounds__(256) void count_kernel(const int* __restrict__ col,
                                                    int* __restrict__ cnt) {
    int e = blockIdx.x * 256 + threadIdx.x;
    if (e < N_EDGES) atomicAdd(&cnt[col[e]], 1);
}

__global__ __launch_bounds__(256) void dinv_kernel(const int* __restrict__ cnt,
                                                   float* __restrict__ dinv) {
    int i = blockIdx.x * 256 + threadIdx.x;
    if (i < N_NODES) dinv[i] = rsqrtf((float)(cnt[i] + 1));  // +1 = self loop
}

// single-block exclusive scan of cnt[0..N) -> off[0..N]
__global__ __launch_bounds__(1024) void scan_kernel(const int* __restrict__ cnt,
                                                    int* __restrict__ off) {
    __shared__ int sdata[1024];
    const int CH = 98;  // 1024*98 = 100352 >= 100000
    int t = threadIdx.x;
    int base = t * CH;
    int lsum = 0;
    for (int i = 0; i < CH; ++i) {
        int idx = base + i;
        if (idx < N_NODES) lsum += cnt[idx];
    }
    sdata[t] = lsum;
    __syncthreads();
    for (int o = 1; o < 1024; o <<= 1) {
        int v = (t >= o) ? sdata[t - o] : 0;
        __syncthreads();
        sdata[t] += v;
        __syncthreads();
    }
    int run = sdata[t] - lsum;  // exclusive prefix for this chunk
    for (int i = 0; i < CH; ++i) {
        int idx = base + i;
        if (idx < N_NODES) {
            off[idx] = run;
            run += cnt[idx];
        } else if (idx == N_NODES) {
            off[idx] = run;  // == total edges
        }
    }
}

__global__ __launch_bounds__(256) void fill_kernel(const int* __restrict__ row,
                                                   const int* __restrict__ col,
                                                   const int* __restrict__ off,
                                                   int* __restrict__ fill,
                                                   const float* __restrict__ dinv,
                                                   int* __restrict__ ssrc,
                                                   float* __restrict__ snorm) {
    int e = blockIdx.x * 256 + threadIdx.x;
    if (e < N_EDGES) {
        int r = row[e], c = col[e];
        int p = off[c] + atomicAdd(&fill[c], 1);
        ssrc[p]  = r;
        snorm[p] = dinv[r] * dinv[c];
    }
}

// graph segment boundaries from sorted batch: gstart[g] = first node with batch>=g
__global__ __launch_bounds__(256) void bounds_kernel(const int* __restrict__ batch,
                                                     int* __restrict__ gstart) {
    int i = blockIdx.x * 256 + threadIdx.x;
    if (i >= N_NODES) return;
    int b  = batch[i];
    int bp = (i == 0) ? -1 : batch[i - 1];
    for (int g = bp + 1; g <= b; ++g) gstart[g] = i;
    if (i == N_NODES - 1) {
        for (int g = b + 1; g <= N_GRAPHS; ++g) gstart[g] = N_NODES;
    }
}

// ---------------- per-layer: aggregate then GEMM ----------------

// one wave per node; halves of the wave process alternating edges;
// lane (l = lane&31) holds dims [4l, 4l+4)
__global__ __launch_bounds__(256) void agg_kernel(const float* __restrict__ h,
                                                  float* __restrict__ out,
                                                  const int* __restrict__ off,
                                                  const int* __restrict__ ssrc,
                                                  const float* __restrict__ snorm,
                                                  const float* __restrict__ dinv) {
    int node = blockIdx.x * 4 + (threadIdx.x >> 6);
    int lane = threadIdx.x & 63;
    int half = lane >> 5;
    int l    = lane & 31;
    const float4* hp = (const float4*)h;

    float4 acc = {0.f, 0.f, 0.f, 0.f};
    if (half == 0) {  // self loop contribution, once
        float di = dinv[node];
        float  w = di * di;
        float4 s = hp[(size_t)node * 32 + l];
        acc.x = w * s.x; acc.y = w * s.y; acc.z = w * s.z; acc.w = w * s.w;
    }

    int beg = off[node], end = off[node + 1];
    int e = beg + half;
    for (; e + 6 < end; e += 8) {
        int   s0 = ssrc[e],     s1 = ssrc[e + 2], s2 = ssrc[e + 4], s3 = ssrc[e + 6];
        float w0 = snorm[e],    w1 = snorm[e + 2], w2 = snorm[e + 4], w3 = snorm[e + 6];
        float4 v0 = hp[(size_t)s0 * 32 + l];
        float4 v1 = hp[(size_t)s1 * 32 + l];
        float4 v2 = hp[(size_t)s2 * 32 + l];
        float4 v3 = hp[(size_t)s3 * 32 + l];
        acc.x = fmaf(w0, v0.x, acc.x); acc.y = fmaf(w0, v0.y, acc.y);
        acc.z = fmaf(w0, v0.z, acc.z); acc.w = fmaf(w0, v0.w, acc.w);
        acc.x = fmaf(w1, v1.x, acc.x); acc.y = fmaf(w1, v1.y, acc.y);
        acc.z = fmaf(w1, v1.z, acc.z); acc.w = fmaf(w1, v1.w, acc.w);
        acc.x = fmaf(w2, v2.x, acc.x); acc.y = fmaf(w2, v2.y, acc.y);
        acc.z = fmaf(w2, v2.z, acc.z); acc.w = fmaf(w2, v2.w, acc.w);
        acc.x = fmaf(w3, v3.x, acc.x); acc.y = fmaf(w3, v3.y, acc.y);
        acc.z = fmaf(w3, v3.z, acc.z); acc.w = fmaf(w3, v3.w, acc.w);
    }
    for (; e < end; e += 2) {
        int s = ssrc[e];
        float w = snorm[e];
        float4 v = hp[(size_t)s * 32 + l];
        acc.x = fmaf(w, v.x, acc.x); acc.y = fmaf(w, v.y, acc.y);
        acc.z = fmaf(w, v.z, acc.z); acc.w = fmaf(w, v.w, acc.w);
    }

    // combine the two halves (lane <-> lane^32)
    acc.x += __shfl_xor(acc.x, 32);
    acc.y += __shfl_xor(acc.y, 32);
    acc.z += __shfl_xor(acc.z, 32);
    acc.w += __shfl_xor(acc.w, 32);
    if (half == 0) ((float4*)out)[(size_t)node * 32 + l] = acc;
}

// C[m, j] = relu_opt( sum_k A[m,k] * W[k,j] + bias[j] ), tile 64 nodes x 128 outs
__global__ __launch_bounds__(256) void gemm_kernel(const float* __restrict__ A,
                                                   const float* __restrict__ W,
                                                   const float* __restrict__ bias,
                                                   float* __restrict__ out,
                                                   int do_relu) {
    __shared__ float sW[32][132];  // k-chunk x 128 outputs (+4 pad)
    __shared__ float sA[32][68];   // k-chunk x 64 nodes (+4 pad)
    int t  = threadIdx.x;
    int m0 = blockIdx.x * 64;
    int jt = (t & 15) * 8;   // output base for this thread
    int mt = (t >> 4) * 4;   // node base for this thread

    float acc[4][8];
#pragma unroll
    for (int i = 0; i < 4; ++i)
#pragma unroll
        for (int j = 0; j < 8; ++j) acc[i][j] = 0.f;

    for (int k0 = 0; k0 < 128; k0 += 32) {
        __syncthreads();
        {   // stage A chunk (transposed): 64 m x 32 k
            int ml = t >> 2, kl = (t & 3) * 8;
            int m = m0 + ml;
            float4 v0 = {0, 0, 0, 0}, v1 = {0, 0, 0, 0};
            if (m < N_NODES) {
                const float4* ap = (const float4*)(A + (size_t)m * 128 + k0 + kl);
                v0 = ap[0];
                v1 = ap[1];
            }
            sA[kl + 0][ml] = v0.x; sA[kl + 1][ml] = v0.y;
            sA[kl + 2][ml] = v0.z; sA[kl + 3][ml] = v0.w;
            sA[kl + 4][ml] = v1.x; sA[kl + 5][ml] = v1.y;
            sA[kl + 6][ml] = v1.z; sA[kl + 7][ml] = v1.w;
        }
        {   // stage W chunk: 32 k x 128 j
            int kw = t >> 3, jw = (t & 7) * 16;
            const float* wp = W + (size_t)(k0 + kw) * 128 + jw;
            float4 w0 = ((const float4*)wp)[0];
            float4 w1 = ((const float4*)wp)[1];
            float4 w2 = ((const float4*)wp)[2];
            float4 w3 = ((const float4*)wp)[3];
            *(float4*)&sW[kw][jw + 0]  = w0;
            *(float4*)&sW[kw][jw + 4]  = w1;
            *(float4*)&sW[kw][jw + 8]  = w2;
            *(float4*)&sW[kw][jw + 12] = w3;
        }
        __syncthreads();
#pragma unroll
        for (int kk = 0; kk < 32; ++kk) {
            float4 a  = *(const float4*)&sA[kk][mt];
            float4 w0 = *(const float4*)&sW[kk][jt];
            float4 w1 = *(const float4*)&sW[kk][jt + 4];
            float av[4] = {a.x, a.y, a.z, a.w};
            float wv[8] = {w0.x, w0.y, w0.z, w0.w, w1.x, w1.y, w1.z, w1.w};
#pragma unroll
            for (int i = 0; i < 4; ++i)
#pragma unroll
                for (int j = 0; j < 8; ++j)
                    acc[i][j] = fmaf(av[i], wv[j], acc[i][j]);
        }
    }

#pragma unroll
    for (int i = 0; i < 4; ++i) {
        int m = m0 + mt + i;
        if (m < N_NODES) {
            float4 o0, o1;
            o0.x = acc[i][0] + bias[jt + 0];
            o0.y = acc[i][1] + bias[jt + 1];
            o0.z = acc[i][2] + bias[jt + 2];
            o0.w = acc[i][3] + bias[jt + 3];
            o1.x = acc[i][4] + bias[jt + 4];
            o1.y = acc[i][5] + bias[jt + 5];
            o1.z = acc[i][6] + bias[jt + 6];
            o1.w = acc[i][7] + bias[jt + 7];
            if (do_relu) {
                o0.x = fmaxf(o0.x, 0.f); o0.y = fmaxf(o0.y, 0.f);
                o0.z = fmaxf(o0.z, 0.f); o0.w = fmaxf(o0.w, 0.f);
                o1.x = fmaxf(o1.x, 0.f); o1.y = fmaxf(o1.y, 0.f);
                o1.z = fmaxf(o1.z, 0.f); o1.w = fmaxf(o1.w, 0.f);
            }
            *(float4*)(out + (size_t)m * 128 + jt)     = o0;
            *(float4*)(out + (size_t)m * 128 + jt + 4) = o1;
        }
    }
}

// ---------------- pooling + MLP head ----------------

// one block per graph; segment [gstart[g], gstart[g+1]) is contiguous (batch sorted)
__global__ __launch_bounds__(256) void pool_kernel(const float* __restrict__ h,
                                                   const int* __restrict__ gstart,
                                                   float* __restrict__ pooled) {
    __shared__ float part[128];
    int g = blockIdx.x;
    int s = gstart[g], e2 = gstart[g + 1];
    int dim   = threadIdx.x & 127;
    int which = threadIdx.x >> 7;  // 0 or 1: even/odd nodes

    float acc = 0.f;
    int n = s + which;
    for (; n + 6 < e2; n += 8) {
        float a0 = h[(size_t)(n    ) * 128 + dim];
        float a1 = h[(size_t)(n + 2) * 128 + dim];
        float a2 = h[(size_t)(n + 4) * 128 + dim];
        float a3 = h[(size_t)(n + 6) * 128 + dim];
        acc += (a0 + a1) + (a2 + a3);
    }
    for (; n < e2; n += 2) acc += h[(size_t)n * 128 + dim];

    if (which == 1) part[dim] = acc;
    __syncthreads();
    if (which == 0) {
        float tot = acc + part[dim];
        float cnt = fmaxf((float)(e2 - s), 1.0f);
        pooled[(size_t)g * 128 + dim] = tot / cnt;
    }
}

__global__ __launch_bounds__(128) void mlp_kernel(const float* __restrict__ pooled,
                                                  const float* __restrict__ w1,
                                                  const float* __restrict__ b1,
                                                  const float* __restrict__ w2,
                                                  const float* __restrict__ b2,
                                                  float* __restrict__ out) {
    __shared__ float mean[128];
    __shared__ float hid[100];
    int g = blockIdx.x;
    int t = threadIdx.x;
    mean[t] = pooled[(size_t)g * 128 + t];
    __syncthreads();
    if (t < 100) {
        float s = b1[t];
        for (int k = 0; k < 128; ++k) s = fmaf(mean[k], w1[k * 100 + t], s);
        hid[t] = fmaxf(s, 0.f);
    }
    __syncthreads();
    if (t < 4) {
        float s = b2[t];
        for (int j = 0; j < 100; ++j) s = fmaf(hid[j], w2[j * 4 + t], s);
        out[(size_t)g * 4 + t] = s;
    }
}

// ---------------- launch ----------------

extern "C" void kernel_launch(void* const* d_in, const int* in_sizes, int n_in,
                              void* d_out, int out_size, void* d_ws, size_t ws_size,
                              hipStream_t stream) {
    const float* x   = (const float*)d_in[0];
    const float* Ws  = (const float*)d_in[1];
    const float* bs  = (const float*)d_in[2];
    const float* w1  = (const float*)d_in[3];
    const float* b1  = (const float*)d_in[4];
    const float* w2  = (const float*)d_in[5];
    const float* b2  = (const float*)d_in[6];
    const int*   ei  = (const int*)d_in[7];
    const int*   bat = (const int*)d_in[8];
    float* outp = (float*)d_out;

    char* p = (char*)d_ws;
    auto take = [&](size_t bytes) -> void* {
        void* r = (void*)p;
        p += (bytes + 255) & ~(size_t)255;
        return r;
    };
    int*   cnt    = (int*)take((size_t)N_NODES * 4);
    int*   fillc  = (int*)take((size_t)N_NODES * 4);
    int*   csr    = (int*)take((size_t)(N_NODES + 1) * 4);
    float* dinv   = (float*)take((size_t)N_NODES * 4);
    int*   ssrc   = (int*)take((size_t)N_EDGES * 4);
    float* snorm  = (float*)take((size_t)N_EDGES * 4);
    float* pooled = (float*)take((size_t)N_GRAPHS * 128 * 4);
    int*   gstart = (int*)take((size_t)(N_GRAPHS + 1) * 4);
    float* bufA   = (float*)take((size_t)N_NODES * 128 * 4);
    float* bufB   = (float*)take((size_t)N_NODES * 128 * 4);

    const int* row = ei;
    const int* col = ei + N_EDGES;

    hipMemsetAsync(cnt,   0, (size_t)N_NODES * 4, stream);
    hipMemsetAsync(fillc, 0, (size_t)N_NODES * 4, stream);

    count_kernel<<<N_EDGES / 256, 256, 0, stream>>>(col, cnt);
    dinv_kernel<<<(N_NODES + 255) / 256, 256, 0, stream>>>(cnt, dinv);
    scan_kernel<<<1, 1024, 0, stream>>>(cnt, csr);
    fill_kernel<<<N_EDGES / 256, 256, 0, stream>>>(row, col, csr, fillc, dinv, ssrc, snorm);
    bounds_kernel<<<(N_NODES + 255) / 256, 256, 0, stream>>>(bat, gstart);

    const float* hin = x;
    for (int L = 0; L < 4; ++L) {
        agg_kernel<<<N_NODES / 4, 256, 0, stream>>>(hin, bufB, csr, ssrc, snorm, dinv);
        gemm_kernel<<<(N_NODES + 63) / 64, 256, 0, stream>>>(
            bufB, Ws + (size_t)L * 128 * 128, bs + (size_t)L * 128, bufA, (L < 3) ? 1 : 0);
        hin = bufA;
    }
    pool_kernel<<<N_GRAPHS, 256, 0, stream>>>(bufA, gstart, pooled);
    mlp_kernel<<<N_GRAPHS, 128, 0, stream>>>(pooled, w1, b1, w2, b2, outp);
}

// Round 3
// 958.936 us; speedup vs baseline: 1.4343x; 1.1799x over previous
//
#include <hip/hip_runtime.h>

#define N_NODES  100000
#define N_EDGES  1600000
#define DIM      128
#define N_GRAPHS 512

#define SCAN_CHUNK 1024
#define SCAN_NB ((N_NODES + SCAN_CHUNK - 1) / SCAN_CHUNK)  // 98

// ---------------- CSR build ----------------

__global__ __launch_bounds__(256) void count_kernel(const int* __restrict__ col,
                                                    int* __restrict__ cnt) {
    int e = blockIdx.x * 256 + threadIdx.x;
    if (e < N_EDGES) atomicAdd(&cnt[col[e]], 1);
}

__global__ __launch_bounds__(256) void dinv_kernel(const int* __restrict__ cnt,
                                                   float* __restrict__ dinv) {
    int i = blockIdx.x * 256 + threadIdx.x;
    if (i < N_NODES) dinv[i] = rsqrtf((float)(cnt[i] + 1));  // +1 = self loop
}

// 3-phase multi-block exclusive scan of cnt[0..N) -> off[0..N]
__global__ __launch_bounds__(256) void scan_bsum(const int* __restrict__ cnt,
                                                 int* __restrict__ bsum) {
    __shared__ int sd[256];
    int b = blockIdx.x, t = threadIdx.x;
    int base = b * SCAN_CHUNK + t * 4;
    int v = 0;
    if (base + 3 < N_NODES) {
        int4 c = *(const int4*)(cnt + base);
        v = c.x + c.y + c.z + c.w;
    } else {
#pragma unroll
        for (int i = 0; i < 4; ++i)
            if (base + i < N_NODES) v += cnt[base + i];
    }
    sd[t] = v;
    __syncthreads();
#pragma unroll
    for (int o = 128; o > 0; o >>= 1) {
        if (t < o) sd[t] += sd[t + o];
        __syncthreads();
    }
    if (t == 0) bsum[b] = sd[0];
}

__global__ __launch_bounds__(128) void scan_bpre(const int* __restrict__ bsum,
                                                 int* __restrict__ bpre) {
    __shared__ int sd[128];
    int t = threadIdx.x;
    int v = (t < SCAN_NB) ? bsum[t] : 0;
    sd[t] = v;
    __syncthreads();
#pragma unroll
    for (int o = 1; o < 128; o <<= 1) {
        int u = (t >= o) ? sd[t - o] : 0;
        __syncthreads();
        sd[t] += u;
        __syncthreads();
    }
    if (t < SCAN_NB) bpre[t] = sd[t] - v;  // exclusive block prefix
}

__global__ __launch_bounds__(256) void scan_final(const int* __restrict__ cnt,
                                                  const int* __restrict__ bpre,
                                                  int* __restrict__ off) {
    __shared__ int sd[256];
    int b = blockIdx.x, t = threadIdx.x;
    int base = b * SCAN_CHUNK + t * 4;
    int c0 = 0, c1 = 0, c2 = 0, c3 = 0;
    if (base + 3 < N_NODES) {
        int4 c = *(const int4*)(cnt + base);
        c0 = c.x; c1 = c.y; c2 = c.z; c3 = c.w;
    } else {
        if (base + 0 < N_NODES) c0 = cnt[base + 0];
        if (base + 1 < N_NODES) c1 = cnt[base + 1];
        if (base + 2 < N_NODES) c2 = cnt[base + 2];
    }
    int lsum = c0 + c1 + c2 + c3;
    sd[t] = lsum;
    __syncthreads();
#pragma unroll
    for (int o = 1; o < 256; o <<= 1) {
        int u = (t >= o) ? sd[t - o] : 0;
        __syncthreads();
        sd[t] += u;
        __syncthreads();
    }
    int run = bpre[b] + sd[t] - lsum;
    int o0 = run, o1 = run + c0, o2 = o1 + c1, o3 = o2 + c2;
    if (base + 3 < N_NODES) {
        int4 ov; ov.x = o0; ov.y = o1; ov.z = o2; ov.w = o3;
        *(int4*)(off + base) = ov;
    } else {
        if (base + 0 < N_NODES) off[base + 0] = o0;
        if (base + 1 < N_NODES) off[base + 1] = o1;
        if (base + 2 < N_NODES) off[base + 2] = o2;
    }
    if (b == 0 && t == 0) off[N_NODES] = N_EDGES;  // all targets in [0, N)
}

__global__ __launch_bounds__(256) void fill_kernel(const int* __restrict__ row,
                                                   const int* __restrict__ col,
                                                   const int* __restrict__ off,
                                                   int* __restrict__ fill,
                                                   const float* __restrict__ dinv,
                                                   int* __restrict__ ssrc,
                                                   float* __restrict__ snorm) {
    int e = blockIdx.x * 256 + threadIdx.x;
    if (e < N_EDGES) {
        int r = row[e], c = col[e];
        int p = off[c] + atomicAdd(&fill[c], 1);
        ssrc[p]  = r;
        snorm[p] = dinv[r] * dinv[c];
    }
}

// graph segment boundaries from sorted batch: gstart[g] = first node with batch>=g
__global__ __launch_bounds__(256) void bounds_kernel(const int* __restrict__ batch,
                                                     int* __restrict__ gstart) {
    int i = blockIdx.x * 256 + threadIdx.x;
    if (i >= N_NODES) return;
    int b  = batch[i];
    int bp = (i == 0) ? -1 : batch[i - 1];
    for (int g = bp + 1; g <= b; ++g) gstart[g] = i;
    if (i == N_NODES - 1) {
        for (int g = b + 1; g <= N_GRAPHS; ++g) gstart[g] = N_NODES;
    }
}

// ---------------- per-layer: aggregate then GEMM ----------------

// one wave per node; halves of the wave process alternating edges;
// lane (l = lane&31) holds dims [4l, 4l+4)
__global__ __launch_bounds__(256) void agg_kernel(const float* __restrict__ h,
                                                  float* __restrict__ out,
                                                  const int* __restrict__ off,
                                                  const int* __restrict__ ssrc,
                                                  const float* __restrict__ snorm,
                                                  const float* __restrict__ dinv) {
    int node = blockIdx.x * 4 + (threadIdx.x >> 6);
    int lane = threadIdx.x & 63;
    int half = lane >> 5;
    int l    = lane & 31;
    const float4* hp = (const float4*)h;

    float4 acc = {0.f, 0.f, 0.f, 0.f};
    if (half == 0) {  // self loop contribution, once
        float di = dinv[node];
        float  w = di * di;
        float4 s = hp[(size_t)node * 32 + l];
        acc.x = w * s.x; acc.y = w * s.y; acc.z = w * s.z; acc.w = w * s.w;
    }

    int beg = off[node], end = off[node + 1];
    int e = beg + half;
    for (; e + 6 < end; e += 8) {
        int   s0 = ssrc[e],     s1 = ssrc[e + 2], s2 = ssrc[e + 4], s3 = ssrc[e + 6];
        float w0 = snorm[e],    w1 = snorm[e + 2], w2 = snorm[e + 4], w3 = snorm[e + 6];
        float4 v0 = hp[(size_t)s0 * 32 + l];
        float4 v1 = hp[(size_t)s1 * 32 + l];
        float4 v2 = hp[(size_t)s2 * 32 + l];
        float4 v3 = hp[(size_t)s3 * 32 + l];
        acc.x = fmaf(w0, v0.x, acc.x); acc.y = fmaf(w0, v0.y, acc.y);
        acc.z = fmaf(w0, v0.z, acc.z); acc.w = fmaf(w0, v0.w, acc.w);
        acc.x = fmaf(w1, v1.x, acc.x); acc.y = fmaf(w1, v1.y, acc.y);
        acc.z = fmaf(w1, v1.z, acc.z); acc.w = fmaf(w1, v1.w, acc.w);
        acc.x = fmaf(w2, v2.x, acc.x); acc.y = fmaf(w2, v2.y, acc.y);
        acc.z = fmaf(w2, v2.z, acc.z); acc.w = fmaf(w2, v2.w, acc.w);
        acc.x = fmaf(w3, v3.x, acc.x); acc.y = fmaf(w3, v3.y, acc.y);
        acc.z = fmaf(w3, v3.z, acc.z); acc.w = fmaf(w3, v3.w, acc.w);
    }
    for (; e < end; e += 2) {
        int s = ssrc[e];
        float w = snorm[e];
        float4 v = hp[(size_t)s * 32 + l];
        acc.x = fmaf(w, v.x, acc.x); acc.y = fmaf(w, v.y, acc.y);
        acc.z = fmaf(w, v.z, acc.z); acc.w = fmaf(w, v.w, acc.w);
    }

    // combine the two halves (lane <-> lane^32)
    acc.x += __shfl_xor(acc.x, 32);
    acc.y += __shfl_xor(acc.y, 32);
    acc.z += __shfl_xor(acc.z, 32);
    acc.w += __shfl_xor(acc.w, 32);
    if (half == 0) ((float4*)out)[(size_t)node * 32 + l] = acc;
}

// C[m, j] = relu_opt( sum_k A[m,k] * W[k,j] + bias[j] ), tile 64 nodes x 128 outs
__global__ __launch_bounds__(256) void gemm_kernel(const float* __restrict__ A,
                                                   const float* __restrict__ W,
                                                   const float* __restrict__ bias,
                                                   float* __restrict__ out,
                                                   int do_relu) {
    __shared__ float sW[32][132];  // k-chunk x 128 outputs (+4 pad)
    __shared__ float sA[32][68];   // k-chunk x 64 nodes (+4 pad)
    int t  = threadIdx.x;
    int m0 = blockIdx.x * 64;
    int jt = (t & 15) * 8;   // output base for this thread
    int mt = (t >> 4) * 4;   // node base for this thread

    float acc[4][8];
#pragma unroll
    for (int i = 0; i < 4; ++i)
#pragma unroll
        for (int j = 0; j < 8; ++j) acc[i][j] = 0.f;

    for (int k0 = 0; k0 < 128; k0 += 32) {
        __syncthreads();
        {   // stage A chunk (transposed): 64 m x 32 k
            int ml = t >> 2, kl = (t & 3) * 8;
            int m = m0 + ml;
            float4 v0 = {0, 0, 0, 0}, v1 = {0, 0, 0, 0};
            if (m < N_NODES) {
                const float4* ap = (const float4*)(A + (size_t)m * 128 + k0 + kl);
                v0 = ap[0];
                v1 = ap[1];
            }
            sA[kl + 0][ml] = v0.x; sA[kl + 1][ml] = v0.y;
            sA[kl + 2][ml] = v0.z; sA[kl + 3][ml] = v0.w;
            sA[kl + 4][ml] = v1.x; sA[kl + 5][ml] = v1.y;
            sA[kl + 6][ml] = v1.z; sA[kl + 7][ml] = v1.w;
        }
        {   // stage W chunk: 32 k x 128 j
            int kw = t >> 3, jw = (t & 7) * 16;
            const float* wp = W + (size_t)(k0 + kw) * 128 + jw;
            float4 w0 = ((const float4*)wp)[0];
            float4 w1 = ((const float4*)wp)[1];
            float4 w2 = ((const float4*)wp)[2];
            float4 w3 = ((const float4*)wp)[3];
            *(float4*)&sW[kw][jw + 0]  = w0;
            *(float4*)&sW[kw][jw + 4]  = w1;
            *(float4*)&sW[kw][jw + 8]  = w2;
            *(float4*)&sW[kw][jw + 12] = w3;
        }
        __syncthreads();
#pragma unroll
        for (int kk = 0; kk < 32; ++kk) {
            float4 a  = *(const float4*)&sA[kk][mt];
            float4 w0 = *(const float4*)&sW[kk][jt];
            float4 w1 = *(const float4*)&sW[kk][jt + 4];
            float av[4] = {a.x, a.y, a.z, a.w};
            float wv[8] = {w0.x, w0.y, w0.z, w0.w, w1.x, w1.y, w1.z, w1.w};
#pragma unroll
            for (int i = 0; i < 4; ++i)
#pragma unroll
                for (int j = 0; j < 8; ++j)
                    acc[i][j] = fmaf(av[i], wv[j], acc[i][j]);
        }
    }

#pragma unroll
    for (int i = 0; i < 4; ++i) {
        int m = m0 + mt + i;
        if (m < N_NODES) {
            float4 o0, o1;
            o0.x = acc[i][0] + bias[jt + 0];
            o0.y = acc[i][1] + bias[jt + 1];
            o0.z = acc[i][2] + bias[jt + 2];
            o0.w = acc[i][3] + bias[jt + 3];
            o1.x = acc[i][4] + bias[jt + 4];
            o1.y = acc[i][5] + bias[jt + 5];
            o1.z = acc[i][6] + bias[jt + 6];
            o1.w = acc[i][7] + bias[jt + 7];
            if (do_relu) {
                o0.x = fmaxf(o0.x, 0.f); o0.y = fmaxf(o0.y, 0.f);
                o0.z = fmaxf(o0.z, 0.f); o0.w = fmaxf(o0.w, 0.f);
                o1.x = fmaxf(o1.x, 0.f); o1.y = fmaxf(o1.y, 0.f);
                o1.z = fmaxf(o1.z, 0.f); o1.w = fmaxf(o1.w, 0.f);
            }
            *(float4*)(out + (size_t)m * 128 + jt)     = o0;
            *(float4*)(out + (size_t)m * 128 + jt + 4) = o1;
        }
    }
}

// ---------------- pooling + MLP head ----------------

// one block per graph; segment [gstart[g], gstart[g+1]) is contiguous (batch sorted)
__global__ __launch_bounds__(256) void pool_kernel(const float* __restrict__ h,
                                                   const int* __restrict__ gstart,
                                                   float* __restrict__ pooled) {
    __shared__ float part[128];
    int g = blockIdx.x;
    int s = gstart[g], e2 = gstart[g + 1];
    int dim   = threadIdx.x & 127;
    int which = threadIdx.x >> 7;  // 0 or 1: even/odd nodes

    float acc = 0.f;
    int n = s + which;
    for (; n + 6 < e2; n += 8) {
        float a0 = h[(size_t)(n    ) * 128 + dim];
        float a1 = h[(size_t)(n + 2) * 128 + dim];
        float a2 = h[(size_t)(n + 4) * 128 + dim];
        float a3 = h[(size_t)(n + 6) * 128 + dim];
        acc += (a0 + a1) + (a2 + a3);
    }
    for (; n < e2; n += 2) acc += h[(size_t)n * 128 + dim];

    if (which == 1) part[dim] = acc;
    __syncthreads();
    if (which == 0) {
        float tot = acc + part[dim];
        float cnt = fmaxf((float)(e2 - s), 1.0f);
        pooled[(size_t)g * 128 + dim] = tot / cnt;
    }
}

__global__ __launch_bounds__(128) void mlp_kernel(const float* __restrict__ pooled,
                                                  const float* __restrict__ w1,
                                                  const float* __restrict__ b1,
                                                  const float* __restrict__ w2,
                                                  const float* __restrict__ b2,
                                                  float* __restrict__ out) {
    __shared__ float mean[128];
    __shared__ float hid[100];
    int g = blockIdx.x;
    int t = threadIdx.x;
    mean[t] = pooled[(size_t)g * 128 + t];
    __syncthreads();
    if (t < 100) {
        float s = b1[t];
        for (int k = 0; k < 128; ++k) s = fmaf(mean[k], w1[k * 100 + t], s);
        hid[t] = fmaxf(s, 0.f);
    }
    __syncthreads();
    if (t < 4) {
        float s = b2[t];
        for (int j = 0; j < 100; ++j) s = fmaf(hid[j], w2[j * 4 + t], s);
        out[(size_t)g * 4 + t] = s;
    }
}

// ---------------- launch ----------------

extern "C" void kernel_launch(void* const* d_in, const int* in_sizes, int n_in,
                              void* d_out, int out_size, void* d_ws, size_t ws_size,
                              hipStream_t stream) {
    const float* x   = (const float*)d_in[0];
    const float* Ws  = (const float*)d_in[1];
    const float* bs  = (const float*)d_in[2];
    const float* w1  = (const float*)d_in[3];
    const float* b1  = (const float*)d_in[4];
    const float* w2  = (const float*)d_in[5];
    const float* b2  = (const float*)d_in[6];
    const int*   ei  = (const int*)d_in[7];
    const int*   bat = (const int*)d_in[8];
    float* outp = (float*)d_out;

    char* p = (char*)d_ws;
    auto take = [&](size_t bytes) -> void* {
        void* r = (void*)p;
        p += (bytes + 255) & ~(size_t)255;
        return r;
    };
    int*   cnt    = (int*)take((size_t)N_NODES * 4);
    int*   fillc  = (int*)take((size_t)N_NODES * 4);
    int*   csr    = (int*)take((size_t)(N_NODES + 1) * 4);
    float* dinv   = (float*)take((size_t)N_NODES * 4);
    int*   bsum   = (int*)take((size_t)SCAN_NB * 4);
    int*   bpre   = (int*)take((size_t)SCAN_NB * 4);
    int*   ssrc   = (int*)take((size_t)N_EDGES * 4);
    float* snorm  = (float*)take((size_t)N_EDGES * 4);
    float* pooled = (float*)take((size_t)N_GRAPHS * 128 * 4);
    int*   gstart = (int*)take((size_t)(N_GRAPHS + 1) * 4);
    float* bufA   = (float*)take((size_t)N_NODES * 128 * 4);
    float* bufB   = (float*)take((size_t)N_NODES * 128 * 4);

    const int* row = ei;
    const int* col = ei + N_EDGES;

    hipMemsetAsync(cnt,   0, (size_t)N_NODES * 4, stream);
    hipMemsetAsync(fillc, 0, (size_t)N_NODES * 4, stream);

    count_kernel<<<N_EDGES / 256, 256, 0, stream>>>(col, cnt);
    dinv_kernel<<<(N_NODES + 255) / 256, 256, 0, stream>>>(cnt, dinv);
    scan_bsum<<<SCAN_NB, 256, 0, stream>>>(cnt, bsum);
    scan_bpre<<<1, 128, 0, stream>>>(bsum, bpre);
    scan_final<<<SCAN_NB, 256, 0, stream>>>(cnt, bpre, csr);
    fill_kernel<<<N_EDGES / 256, 256, 0, stream>>>(row, col, csr, fillc, dinv, ssrc, snorm);
    bounds_kernel<<<(N_NODES + 255) / 256, 256, 0, stream>>>(bat, gstart);

    const float* hin = x;
    for (int L = 0; L < 4; ++L) {
        agg_kernel<<<N_NODES / 4, 256, 0, stream>>>(hin, bufB, csr, ssrc, snorm, dinv);
        gemm_kernel<<<(N_NODES + 63) / 64, 256, 0, stream>>>(
            bufB, Ws + (size_t)L * 128 * 128, bs + (size_t)L * 128, bufA, (L < 3) ? 1 : 0);
        hin = bufA;
    }
    pool_kernel<<<N_GRAPHS, 256, 0, stream>>>(bufA, gstart, pooled);
    mlp_kernel<<<N_GRAPHS, 128, 0, stream>>>(pooled, w1, b1, w2, b2, outp);
}

// Round 4
// 706.938 us; speedup vs baseline: 1.9456x; 1.3565x over previous
//
#include <hip/hip_runtime.h>

#define N_NODES  100000
#define N_EDGES  1600000
#define DIM      128
#define N_GRAPHS 512

#define SCAN_CHUNK 1024
#define SCAN_NB ((N_NODES + SCAN_CHUNK - 1) / SCAN_CHUNK)  // 98

typedef short  bf16x8 __attribute__((ext_vector_type(8)));
typedef float  f32x4  __attribute__((ext_vector_type(4)));

__device__ inline ushort f2bf(float f) {  // round-to-nearest-even
    union { float f; unsigned u; } v; v.f = f;
    unsigned r = v.u + 0x7FFFu + ((v.u >> 16) & 1u);
    return (ushort)(r >> 16);
}
__device__ inline float bf2f_lo(unsigned u) { union { unsigned u; float f; } v; v.u = u << 16; return v.f; }
__device__ inline float bf2f_hi(unsigned u) { union { unsigned u; float f; } v; v.u = u & 0xFFFF0000u; return v.f; }

// ---------------- dtype conversion ----------------

__global__ __launch_bounds__(256) void cvt_x(const float* __restrict__ x,
                                             ushort* __restrict__ xb) {
    int i = (blockIdx.x * 256 + threadIdx.x) * 4;  // 12.8M elements, exact
    float4 v = *(const float4*)(x + i);
    ushort4 o;
    o.x = f2bf(v.x); o.y = f2bf(v.y); o.z = f2bf(v.z); o.w = f2bf(v.w);
    *(ushort4*)(xb + i) = o;
}

// WT[L][n][k] = Ws[L][k][n], bf16
__global__ __launch_bounds__(256) void cvt_w(const float* __restrict__ Ws,
                                             ushort* __restrict__ WT) {
    int idx = blockIdx.x * 256 + threadIdx.x;  // 65536 total
    int L = idx >> 14, n = (idx >> 7) & 127, k = idx & 127;
    WT[idx] = f2bf(Ws[(L << 14) + (k << 7) + n]);
}

// ---------------- CSR build ----------------

__global__ __launch_bounds__(256) void count_kernel(const int* __restrict__ col,
                                                    int* __restrict__ cnt) {
    int e = blockIdx.x * 256 + threadIdx.x;
    if (e < N_EDGES) atomicAdd(&cnt[col[e]], 1);
}

__global__ __launch_bounds__(256) void dinv_kernel(const int* __restrict__ cnt,
                                                   float* __restrict__ dinv) {
    int i = blockIdx.x * 256 + threadIdx.x;
    if (i < N_NODES) dinv[i] = rsqrtf((float)(cnt[i] + 1));  // +1 = self loop
}

__global__ __launch_bounds__(256) void scan_bsum(const int* __restrict__ cnt,
                                                 int* __restrict__ bsum) {
    __shared__ int sd[256];
    int b = blockIdx.x, t = threadIdx.x;
    int base = b * SCAN_CHUNK + t * 4;
    int v = 0;
    if (base + 3 < N_NODES) {
        int4 c = *(const int4*)(cnt + base);
        v = c.x + c.y + c.z + c.w;
    } else {
#pragma unroll
        for (int i = 0; i < 4; ++i)
            if (base + i < N_NODES) v += cnt[base + i];
    }
    sd[t] = v;
    __syncthreads();
#pragma unroll
    for (int o = 128; o > 0; o >>= 1) {
        if (t < o) sd[t] += sd[t + o];
        __syncthreads();
    }
    if (t == 0) bsum[b] = sd[0];
}

__global__ __launch_bounds__(128) void scan_bpre(const int* __restrict__ bsum,
                                                 int* __restrict__ bpre) {
    __shared__ int sd[128];
    int t = threadIdx.x;
    int v = (t < SCAN_NB) ? bsum[t] : 0;
    sd[t] = v;
    __syncthreads();
#pragma unroll
    for (int o = 1; o < 128; o <<= 1) {
        int u = (t >= o) ? sd[t - o] : 0;
        __syncthreads();
        sd[t] += u;
        __syncthreads();
    }
    if (t < SCAN_NB) bpre[t] = sd[t] - v;
}

__global__ __launch_bounds__(256) void scan_final(const int* __restrict__ cnt,
                                                  const int* __restrict__ bpre,
                                                  int* __restrict__ off) {
    __shared__ int sd[256];
    int b = blockIdx.x, t = threadIdx.x;
    int base = b * SCAN_CHUNK + t * 4;
    int c0 = 0, c1 = 0, c2 = 0, c3 = 0;
    if (base + 3 < N_NODES) {
        int4 c = *(const int4*)(cnt + base);
        c0 = c.x; c1 = c.y; c2 = c.z; c3 = c.w;
    } else {
        if (base + 0 < N_NODES) c0 = cnt[base + 0];
        if (base + 1 < N_NODES) c1 = cnt[base + 1];
        if (base + 2 < N_NODES) c2 = cnt[base + 2];
    }
    int lsum = c0 + c1 + c2 + c3;
    sd[t] = lsum;
    __syncthreads();
#pragma unroll
    for (int o = 1; o < 256; o <<= 1) {
        int u = (t >= o) ? sd[t - o] : 0;
        __syncthreads();
        sd[t] += u;
        __syncthreads();
    }
    int run = bpre[b] + sd[t] - lsum;
    int o0 = run, o1 = run + c0, o2 = o1 + c1, o3 = o2 + c2;
    if (base + 3 < N_NODES) {
        int4 ov; ov.x = o0; ov.y = o1; ov.z = o2; ov.w = o3;
        *(int4*)(off + base) = ov;
    } else {
        if (base + 0 < N_NODES) off[base + 0] = o0;
        if (base + 1 < N_NODES) off[base + 1] = o1;
        if (base + 2 < N_NODES) off[base + 2] = o2;
    }
    if (b == 0 && t == 0) off[N_NODES] = N_EDGES;
}

__global__ __launch_bounds__(256) void fill_kernel(const int* __restrict__ row,
                                                   const int* __restrict__ col,
                                                   const int* __restrict__ off,
                                                   int* __restrict__ fill,
                                                   const float* __restrict__ dinv,
                                                   int2* __restrict__ edat) {
    int e = blockIdx.x * 256 + threadIdx.x;
    if (e < N_EDGES) {
        int r = row[e], c = col[e];
        int p = off[c] + atomicAdd(&fill[c], 1);
        float nw = dinv[r] * dinv[c];
        edat[p] = make_int2(r, __float_as_int(nw));
    }
}

__global__ __launch_bounds__(256) void bounds_kernel(const int* __restrict__ batch,
                                                     int* __restrict__ gstart) {
    int i = blockIdx.x * 256 + threadIdx.x;
    if (i >= N_NODES) return;
    int b  = batch[i];
    int bp = (i == 0) ? -1 : batch[i - 1];
    for (int g = bp + 1; g <= b; ++g) gstart[g] = i;
    if (i == N_NODES - 1) {
        for (int g = b + 1; g <= N_GRAPHS; ++g) gstart[g] = N_NODES;
    }
}

// ---------------- aggregate (bf16 gather, fp32 acc, bf16 out) ----------------
// one wave per node; quarter-wave (16 lanes x 16B) reads one 256B row;
// 4 edges in flight per wave. lane l of a quarter holds dims [8l, 8l+8).
__global__ __launch_bounds__(256) void agg_kernel(const ushort* __restrict__ h,
                                                  ushort* __restrict__ out,
                                                  const int* __restrict__ off,
                                                  const int2* __restrict__ edat,
                                                  const float* __restrict__ dinv) {
    int node = blockIdx.x * 4 + (threadIdx.x >> 6);
    int lane = threadIdx.x & 63;
    int q = lane >> 4;
    int l = lane & 15;
    const uint4* hp = (const uint4*)h;  // row = 16 uint4 (256 B)

    float acc[8];
#pragma unroll
    for (int i = 0; i < 8; ++i) acc[i] = 0.f;

    if (q == 0) {  // self loop
        float di = dinv[node];
        float w  = di * di;
        uint4 v = hp[(size_t)node * 16 + l];
        acc[0] = w * bf2f_lo(v.x); acc[1] = w * bf2f_hi(v.x);
        acc[2] = w * bf2f_lo(v.y); acc[3] = w * bf2f_hi(v.y);
        acc[4] = w * bf2f_lo(v.z); acc[5] = w * bf2f_hi(v.z);
        acc[6] = w * bf2f_lo(v.w); acc[7] = w * bf2f_hi(v.w);
    }

    int beg = off[node], end = off[node + 1];
    int e = beg + q;
    for (; e + 12 < end; e += 16) {
        int2 e0 = edat[e], e1 = edat[e + 4], e2 = edat[e + 8], e3 = edat[e + 12];
        uint4 v0 = hp[(size_t)e0.x * 16 + l];
        uint4 v1 = hp[(size_t)e1.x * 16 + l];
        uint4 v2 = hp[(size_t)e2.x * 16 + l];
        uint4 v3 = hp[(size_t)e3.x * 16 + l];
        float w0 = __int_as_float(e0.y), w1 = __int_as_float(e1.y);
        float w2 = __int_as_float(e2.y), w3 = __int_as_float(e3.y);
        acc[0] = fmaf(w0, bf2f_lo(v0.x), acc[0]); acc[1] = fmaf(w0, bf2f_hi(v0.x), acc[1]);
        acc[2] = fmaf(w0, bf2f_lo(v0.y), acc[2]); acc[3] = fmaf(w0, bf2f_hi(v0.y), acc[3]);
        acc[4] = fmaf(w0, bf2f_lo(v0.z), acc[4]); acc[5] = fmaf(w0, bf2f_hi(v0.z), acc[5]);
        acc[6] = fmaf(w0, bf2f_lo(v0.w), acc[6]); acc[7] = fmaf(w0, bf2f_hi(v0.w), acc[7]);
        acc[0] = fmaf(w1, bf2f_lo(v1.x), acc[0]); acc[1] = fmaf(w1, bf2f_hi(v1.x), acc[1]);
        acc[2] = fmaf(w1, bf2f_lo(v1.y), acc[2]); acc[3] = fmaf(w1, bf2f_hi(v1.y), acc[3]);
        acc[4] = fmaf(w1, bf2f_lo(v1.z), acc[4]); acc[5] = fmaf(w1, bf2f_hi(v1.z), acc[5]);
        acc[6] = fmaf(w1, bf2f_lo(v1.w), acc[6]); acc[7] = fmaf(w1, bf2f_hi(v1.w), acc[7]);
        acc[0] = fmaf(w2, bf2f_lo(v2.x), acc[0]); acc[1] = fmaf(w2, bf2f_hi(v2.x), acc[1]);
        acc[2] = fmaf(w2, bf2f_lo(v2.y), acc[2]); acc[3] = fmaf(w2, bf2f_hi(v2.y), acc[3]);
        acc[4] = fmaf(w2, bf2f_lo(v2.z), acc[4]); acc[5] = fmaf(w2, bf2f_hi(v2.z), acc[5]);
        acc[6] = fmaf(w2, bf2f_lo(v2.w), acc[6]); acc[7] = fmaf(w2, bf2f_hi(v2.w), acc[7]);
        acc[0] = fmaf(w3, bf2f_lo(v3.x), acc[0]); acc[1] = fmaf(w3, bf2f_hi(v3.x), acc[1]);
        acc[2] = fmaf(w3, bf2f_lo(v3.y), acc[2]); acc[3] = fmaf(w3, bf2f_hi(v3.y), acc[3]);
        acc[4] = fmaf(w3, bf2f_lo(v3.z), acc[4]); acc[5] = fmaf(w3, bf2f_hi(v3.z), acc[5]);
        acc[6] = fmaf(w3, bf2f_lo(v3.w), acc[6]); acc[7] = fmaf(w3, bf2f_hi(v3.w), acc[7]);
    }
    for (; e < end; e += 4) {
        int2 ed = edat[e];
        float w = __int_as_float(ed.y);
        uint4 v = hp[(size_t)ed.x * 16 + l];
        acc[0] = fmaf(w, bf2f_lo(v.x), acc[0]); acc[1] = fmaf(w, bf2f_hi(v.x), acc[1]);
        acc[2] = fmaf(w, bf2f_lo(v.y), acc[2]); acc[3] = fmaf(w, bf2f_hi(v.y), acc[3]);
        acc[4] = fmaf(w, bf2f_lo(v.z), acc[4]); acc[5] = fmaf(w, bf2f_hi(v.z), acc[5]);
        acc[6] = fmaf(w, bf2f_lo(v.w), acc[6]); acc[7] = fmaf(w, bf2f_hi(v.w), acc[7]);
    }

#pragma unroll
    for (int i = 0; i < 8; ++i) {
        acc[i] += __shfl_xor(acc[i], 16);
        acc[i] += __shfl_xor(acc[i], 32);
    }
    if (q == 0) {
        uint4 ov;
        ov.x = (uint)f2bf(acc[0]) | ((uint)f2bf(acc[1]) << 16);
        ov.y = (uint)f2bf(acc[2]) | ((uint)f2bf(acc[3]) << 16);
        ov.z = (uint)f2bf(acc[4]) | ((uint)f2bf(acc[5]) << 16);
        ov.w = (uint)f2bf(acc[6]) | ((uint)f2bf(acc[7]) << 16);
        ((uint4*)out)[(size_t)node * 16 + l] = ov;
    }
}

// ---------------- GEMM via bf16 MFMA ----------------
// block = 4 waves; wave computes 16 rows x 128 cols. A row-major bf16,
// WT[n][k] bf16 (pre-transposed). A-frag: lane l -> row l&15, k quad*8..+7.
// C/D: col = lane&15, row = (lane>>4)*4 + reg  [m89-verified].
__global__ __launch_bounds__(256) void gemm_mfma(const ushort* __restrict__ A,
                                                 const ushort* __restrict__ WT,
                                                 const float* __restrict__ bias,
                                                 ushort* __restrict__ out,
                                                 int do_relu) {
    int lane = threadIdx.x & 63;
    int wv   = threadIdx.x >> 6;
    int m0   = blockIdx.x * 64 + wv * 16;
    int l15  = lane & 15;
    int kq   = (lane >> 4) * 8;
    int mrow = m0 + l15;
    if (mrow >= N_NODES) mrow = N_NODES - 1;  // clamp; stores guarded

    f32x4 acc[8];
#pragma unroll
    for (int t = 0; t < 8; ++t) acc[t] = (f32x4){0.f, 0.f, 0.f, 0.f};

#pragma unroll
    for (int k0 = 0; k0 < 128; k0 += 32) {
        bf16x8 a = *(const bf16x8*)(A + (size_t)mrow * 128 + k0 + kq);
#pragma unroll
        for (int t = 0; t < 8; ++t) {
            bf16x8 b = *(const bf16x8*)(WT + (size_t)(t * 16 + l15) * 128 + k0 + kq);
            acc[t] = __builtin_amdgcn_mfma_f32_16x16x32_bf16(a, b, acc[t], 0, 0, 0);
        }
    }

    int orow = m0 + (lane >> 4) * 4;
#pragma unroll
    for (int t = 0; t < 8; ++t) {
        int col = t * 16 + l15;
        float bv = bias[col];
#pragma unroll
        for (int r = 0; r < 4; ++r) {
            int m = orow + r;
            if (m < N_NODES) {
                float v = acc[t][r] + bv;
                if (do_relu) v = fmaxf(v, 0.f);
                out[(size_t)m * 128 + col] = f2bf(v);
            }
        }
    }
}

// ---------------- pooling + MLP head ----------------

__global__ __launch_bounds__(256) void pool_kernel(const ushort* __restrict__ h,
                                                   const int* __restrict__ gstart,
                                                   float* __restrict__ pooled) {
    __shared__ float part[4][128];
    int g = blockIdx.x;
    int s = gstart[g], e2 = gstart[g + 1];
    int p     = threadIdx.x & 63;   // uint index (2 dims)
    int which = threadIdx.x >> 6;   // 0..3
    const uint* hu = (const uint*)h;  // row = 64 uints

    float a0 = 0.f, a1 = 0.f;
    for (int n = s + which; n < e2; n += 4) {
        uint v = hu[(size_t)n * 64 + p];
        a0 += bf2f_lo(v);
        a1 += bf2f_hi(v);
    }
    part[which][2 * p]     = a0;
    part[which][2 * p + 1] = a1;
    __syncthreads();
    if (which == 0) {
        float c = fmaxf((float)(e2 - s), 1.0f);
        float t0 = part[0][2 * p] + part[1][2 * p] + part[2][2 * p] + part[3][2 * p];
        float t1 = part[0][2 * p + 1] + part[1][2 * p + 1] + part[2][2 * p + 1] + part[3][2 * p + 1];
        pooled[(size_t)g * 128 + 2 * p]     = t0 / c;
        pooled[(size_t)g * 128 + 2 * p + 1] = t1 / c;
    }
}

__global__ __launch_bounds__(128) void mlp_kernel(const float* __restrict__ pooled,
                                                  const float* __restrict__ w1,
                                                  const float* __restrict__ b1,
                                                  const float* __restrict__ w2,
                                                  const float* __restrict__ b2,
                                                  float* __restrict__ out) {
    __shared__ float mean[128];
    __shared__ float hid[100];
    int g = blockIdx.x;
    int t = threadIdx.x;
    mean[t] = pooled[(size_t)g * 128 + t];
    __syncthreads();
    if (t < 100) {
        float s = b1[t];
        for (int k = 0; k < 128; ++k) s = fmaf(mean[k], w1[k * 100 + t], s);
        hid[t] = fmaxf(s, 0.f);
    }
    __syncthreads();
    if (t < 4) {
        float s = b2[t];
        for (int j = 0; j < 100; ++j) s = fmaf(hid[j], w2[j * 4 + t], s);
        out[(size_t)g * 4 + t] = s;
    }
}

// ---------------- launch ----------------

extern "C" void kernel_launch(void* const* d_in, const int* in_sizes, int n_in,
                              void* d_out, int out_size, void* d_ws, size_t ws_size,
                              hipStream_t stream) {
    const float* x   = (const float*)d_in[0];
    const float* Ws  = (const float*)d_in[1];
    const float* bs  = (const float*)d_in[2];
    const float* w1  = (const float*)d_in[3];
    const float* b1  = (const float*)d_in[4];
    const float* w2  = (const float*)d_in[5];
    const float* b2  = (const float*)d_in[6];
    const int*   ei  = (const int*)d_in[7];
    const int*   bat = (const int*)d_in[8];
    float* outp = (float*)d_out;

    char* p = (char*)d_ws;
    auto take = [&](size_t bytes) -> void* {
        void* r = (void*)p;
        p += (bytes + 255) & ~(size_t)255;
        return r;
    };
    int*    cnt    = (int*)take((size_t)N_NODES * 4);
    int*    fillc  = (int*)take((size_t)N_NODES * 4);
    int*    csr    = (int*)take((size_t)(N_NODES + 1) * 4);
    float*  dinv   = (float*)take((size_t)N_NODES * 4);
    int*    bsum   = (int*)take((size_t)SCAN_NB * 4);
    int*    bpre   = (int*)take((size_t)SCAN_NB * 4);
    int2*   edat   = (int2*)take((size_t)N_EDGES * 8);
    ushort* xb     = (ushort*)take((size_t)N_NODES * 128 * 2);
    ushort* hb     = (ushort*)take((size_t)N_NODES * 128 * 2);
    ushort* aggb   = (ushort*)take((size_t)N_NODES * 128 * 2);
    ushort* WT     = (ushort*)take((size_t)4 * 128 * 128 * 2);
    float*  pooled = (float*)take((size_t)N_GRAPHS * 128 * 4);
    int*    gstart = (int*)take((size_t)(N_GRAPHS + 1) * 4);

    const int* row = ei;
    const int* col = ei + N_EDGES;

    hipMemsetAsync(cnt,   0, (size_t)N_NODES * 4, stream);
    hipMemsetAsync(fillc, 0, (size_t)N_NODES * 4, stream);

    cvt_x<<<12500, 256, 0, stream>>>(x, xb);
    cvt_w<<<256, 256, 0, stream>>>(Ws, WT);
    count_kernel<<<N_EDGES / 256, 256, 0, stream>>>(col, cnt);
    dinv_kernel<<<(N_NODES + 255) / 256, 256, 0, stream>>>(cnt, dinv);
    scan_bsum<<<SCAN_NB, 256, 0, stream>>>(cnt, bsum);
    scan_bpre<<<1, 128, 0, stream>>>(bsum, bpre);
    scan_final<<<SCAN_NB, 256, 0, stream>>>(cnt, bpre, csr);
    fill_kernel<<<N_EDGES / 256, 256, 0, stream>>>(row, col, csr, fillc, dinv, edat);
    bounds_kernel<<<(N_NODES + 255) / 256, 256, 0, stream>>>(bat, gstart);

    const ushort* hin = xb;
    for (int L = 0; L < 4; ++L) {
        agg_kernel<<<N_NODES / 4, 256, 0, stream>>>(hin, aggb, csr, edat, dinv);
        gemm_mfma<<<(N_NODES + 63) / 64, 256, 0, stream>>>(
            aggb, WT + (size_t)L * 128 * 128, bs + (size_t)L * 128, hb, (L < 3) ? 1 : 0);
        hin = hb;
    }
    pool_kernel<<<N_GRAPHS, 256, 0, stream>>>(hb, gstart, pooled);
    mlp_kernel<<<N_GRAPHS, 128, 0, stream>>>(pooled, w1, b1, w2, b2, outp);
}